// Round 14
// baseline (2087.432 us; speedup 1.0000x reference)
//
#include <hip/hip_runtime.h>
#include <hip/hip_bf16.h>
#include <float.h>
#include <math.h>

typedef __hip_bfloat16 bf16;

#define BATCH 32
#define NPTS  1024
#define KNN   20
#define NB    (BATCH*NPTS)      // 32768 nodes
#define NEDGE (NB*KNN)          // 655360 edges

// ---- workspace layout (float units), ws_size-adaptive ----
#define OFF_FLAG 512u
#define OFF_INB  1024u
#define OFF_IDX  988928u          // 655360 ints (idx1 early, idx2 late)
#define OFF_X1   1644288u         // NB*64
#define OFF_X2   3741440u         // NB*128 ; a1 @ OFF_X2, c1 @ OFF_C1 (early)
#define OFF_C1   5838592u
#define OFF_POOL 7935744u         // pool4: 4 x 32*1024
#define SLOW_END 8066816u         // 32.3 MB
#define OFF_B2H  8066816u         // NB*64 (fast path only)
#define FAST_END 10163968u        // 40.7 MB
// ---- layout inside inb (canonical fp32 inputs) ----
#define IN_POSF 0u
#define IN_B1   98304u
#define IN_G1   98368u
#define IN_BE1  98432u
#define IN_B2   98496u
#define IN_G2   98560u
#define IN_BE2  98624u
#define IN_B3   98688u
#define IN_BC2  98752u
#define IN_BL   98880u
#define IN_BM1  99904u
#define IN_BM2  100416u
#define IN_BM3  100672u
#define IN_W1   100736u
#define IN_WBUF 101120u
#define WB_W2   0u
#define WB_W3   4096u
#define WB_WD   8192u            // Wc2 top-bot diff [64x128]
#define WB_WBOT 16384u           // Wc2 bottom      [64x128]
#define WB_WL   24576u
#define WB_WM1  221184u
#define WB_WM2  745472u
#define WB_WM3  876544u
#define IN_TOTAL 987904u

__device__ __forceinline__ float bf2f(bf16 v){ return __bfloat162float(v); }

// register top-20 (unsorted, lex-worst tracked): O(1) replace + rescan, all
// constant-index -> register-resident; no LDS in the hot path.
#define KNN_INS(d_, ci_)                                                     \
  {                                                                          \
    bool ins_ = (d_ < wv) || (d_ == wv && (ci_) < wi);                       \
    if (ins_){                                                               \
      _Pragma("unroll")                                                      \
      for (int p_ = 0; p_ < KNN; p_++){                                      \
        bool at_ = (p_ == wpos);                                             \
        rd[p_] = at_ ? d_   : rd[p_];                                        \
        ri[p_] = at_ ? (ci_): ri[p_];                                        \
      }                                                                      \
      wv = rd[0]; wi = ri[0]; wpos = 0;                                      \
      _Pragma("unroll")                                                      \
      for (int p_ = 1; p_ < KNN; p_++){                                      \
        bool g_ = (rd[p_] > wv) || (rd[p_] == wv && ri[p_] > wi);            \
        wv = g_ ? rd[p_] : wv;  wi = g_ ? ri[p_] : wi;  wpos = g_ ? p_ : wpos;\
      }                                                                      \
    }                                                                        \
  }

// ---------------- dtype sniff (fp32 vs bf16 inputs) ----------------
__global__ void k_sniff(const void* pos_raw, int* flag){
  if (blockIdx.x == 0 && threadIdx.x == 0){
    const unsigned short* h = (const unsigned short*)pos_raw;
    int wild = 0;
    for (int k = 0; k < 16; k++){
      unsigned int bits = ((unsigned int)h[2*k]) << 16;
      float v = __uint_as_float(bits);
      float a = fabsf(v);
      if (a != 0.0f && (v != v || a > 1e10f || a < 1e-10f)) wild++;
    }
    *flag = (wild >= 4) ? 1 : 0;
  }
}

__device__ __forceinline__ float rdv(const void* p, int i, int f){
  return f ? ((const float*)p)[i] : bf2f(((const bf16*)p)[i]);
}

// ---------------- normalize ALL inputs to canonical fp32 buffer ----------------
__global__ __launch_bounds__(256) void k_cvt(
    const void* pos, const void* W1, const void* b1, const void* g1, const void* be1,
    const void* W2, const void* b2, const void* g2, const void* be2,
    const void* W3, const void* b3, const void* Wc2, const void* bc2,
    const void* Wl, const void* bl, const void* Wm1, const void* bm1,
    const void* Wm2, const void* bm2, const void* Wm3, const void* bm3,
    const int* flag, float* inb){
  int id = blockIdx.x*256 + threadIdx.x;
  if (id >= (int)IN_TOTAL) return;
  int f = *flag;
  float v;
  if      (id < 98304)  v = rdv(pos, id, f);
  else if (id < 98368)  v = rdv(b1,  id-98304, f);
  else if (id < 98432)  v = rdv(g1,  id-98368, f);
  else if (id < 98496)  v = rdv(be1, id-98432, f);
  else if (id < 98560)  v = rdv(b2,  id-98496, f);
  else if (id < 98624)  v = rdv(g2,  id-98560, f);
  else if (id < 98688)  v = rdv(be2, id-98624, f);
  else if (id < 98752)  v = rdv(b3,  id-98688, f);
  else if (id < 98880)  v = rdv(bc2, id-98752, f);
  else if (id < 99904)  v = rdv(bl,  id-98880, f);
  else if (id < 100416) v = rdv(bm1, id-99904, f);
  else if (id < 100672) v = rdv(bm2, id-100416, f);
  else if (id < 100712) v = rdv(bm3, id-100672, f);
  else if (id < 100736) v = 0.0f;
  else if (id < 101120) v = rdv(W1,  id-100736, f);
  else {
    int t = id - 101120;
    if      (t < 4096)   v = rdv(W2, t, f);
    else if (t < 8192)   v = rdv(W3, t-4096, f);
    else if (t < 16384){ int u = t-8192;  v = rdv(Wc2, u, f) - rdv(Wc2, 8192+u, f); }
    else if (t < 24576){ int u = t-16384; v = rdv(Wc2, 8192+u, f); }
    else if (t < 221184) v = rdv(Wl,  t-24576, f);
    else if (t < 745472) v = rdv(Wm1, t-221184, f);
    else if (t < 876544) v = rdv(Wm2, t-745472, f);
    else                 v = rdv(Wm3, t-876544, f);
  }
  inb[id] = v;
}

// ---------------- a1/c1: affine decomposition of EdgeConv1 layer1 ----------------
__global__ __launch_bounds__(256) void k_prep1(const float* inb, float* a1, float* c1){
  const float* posf = inb + IN_POSF;
  const float* W1f  = inb + IN_W1;
  const float* b1f  = inb + IN_B1;
  int id = blockIdx.x*256 + threadIdx.x;
  int bn = id >> 6, c = id & 63;
  float p0 = posf[bn*3], p1 = posf[bn*3+1], p2 = posf[bn*3+2];
  float wt0 = W1f[c],     wt1 = W1f[64+c],  wt2 = W1f[128+c];
  float wb0 = W1f[192+c], wb1 = W1f[256+c], wb2 = W1f[320+c];
  float cv = p0*wb0 + p1*wb1 + p2*wb2;
  float av = p0*(wt0-wb0) + p1*(wt1-wb1) + p2*(wt2-wb2) + b1f[c];
  a1[id] = av;  c1[id] = cv;
}

// ---------------- kNN coord space (v3: register unsorted top-20) ----------------
__global__ __launch_bounds__(256, 2) void k_knn1(const float* inb, int* idx1){
  const float* posf = inb + IN_POSF;
  __shared__ float psx[1024], psy[1024], psz[1024], sqs[1024];
  __shared__ float dls[256*21];
  __shared__ int   ils[256*21];
  int bb = blockIdx.x >> 4;
  int qg = blockIdx.x & 15;
  int tid = threadIdx.x;
  int q_l = tid & 63;
  int slot = tid >> 6;
  for (int t = tid; t < 1024; t += 256){
    float x = posf[(bb*1024+t)*3], y = posf[(bb*1024+t)*3+1], z = posf[(bb*1024+t)*3+2];
    psx[t] = x; psy[t] = y; psz[t] = z; sqs[t] = x*x + y*y + z*z;
  }
  __syncthreads();
  int i_l = qg*64 + q_l;
  float xi0 = psx[i_l], xi1 = psy[i_l], xi2 = psz[i_l];
  float sqi = sqs[i_l];
  float rd[KNN]; int ri[KNN];
  #pragma unroll
  for (int p = 0; p < KNN; p++){ rd[p] = FLT_MAX; ri[p] = 65535; }
  float wv = FLT_MAX; int wi = 65535, wpos = 0;
  for (int u = 0; u < 256; u++){
    int jj = 4*u + slot;
    float dot = xi0*psx[jj] + xi1*psy[jj] + xi2*psz[jj];
    float d = sqi + sqs[jj] - 2.0f*dot;
    KNN_INS(d, jj)
  }
  int base = tid*21;
  #pragma unroll
  for (int p = 0; p < KNN; p++){ dls[base+p] = rd[p]; ils[base+p] = ri[p]; }
  __syncthreads();
  if (slot == 0){
    for (int s = 1; s < 4; s++){
      int sb = (s*64 + q_l)*21;
      for (int p = 0; p < KNN; p++){
        float d = dls[sb+p];
        int ci = ils[sb+p];
        KNN_INS(d, ci)
      }
    }
    int gi = bb*1024 + i_l;
    #pragma unroll
    for (int p = 0; p < KNN; p++) idx1[gi*KNN+p] = ri[p];   // unsorted set (downstream is set-sum/max)
  }
}

// ---------------- BN1 stats ----------------
__global__ __launch_bounds__(256) void k_stats1(const float* a1, const float* c1,
                                                const int* idx1, double* stats){
  __shared__ float rs[256], rs2[256];
  int tid = threadIdx.x, c = tid & 63, slot = tid >> 6;
  int base = blockIdx.x * 1024;
  float s = 0.f, s2 = 0.f;
  for (int t = 0; t < 256; t++){
    unsigned e = (unsigned)(base + t*4 + slot);
    int i = (int)(e / 20u);
    int b = i >> 10;
    int j = idx1[e];
    float h = a1[i*64+c] + c1[((b<<10)+j)*64 + c];
    s += h; s2 += h*h;
  }
  rs[tid] = s; rs2[tid] = s2;
  __syncthreads();
  if (slot == 0){
    double ts  = (double)rs[c]  + (double)rs[64+c]  + (double)rs[128+c]  + (double)rs[192+c];
    double ts2 = (double)rs2[c] + (double)rs2[64+c] + (double)rs2[128+c] + (double)rs2[192+c];
    atomicAdd(&stats[c], ts);
    atomicAdd(&stats[64+c], ts2);
  }
}

// ---------------- BN2 stats (slot-stride 68: bank-conflict-free) ----------------
__global__ __launch_bounds__(256) void k_stats2(const float* a1, const float* c1,
    const int* idx1, const float* inb, double* stats){
  __shared__ __align__(16) float W2s[4096];
  __shared__ __align__(16) float buf[16*68];
  __shared__ float rs[64], rs2[64];
  int tid = threadIdx.x;
  const float* wbuf = inb + IN_WBUF;
  for (int t = tid; t < 4096; t += 256) W2s[t] = wbuf[WB_W2 + t];
  if (tid < 64){ rs[tid] = 0.f; rs2[tid] = 0.f; }
  int slot = tid >> 4;
  int cg = tid & 15;
  const double M = (double)NEDGE;
  float sc1[4], sh1[4], bb2[4];
  #pragma unroll
  for (int u = 0; u < 4; u++){
    int c = cg*4 + u;
    double mean = stats[c] / M;
    double var  = stats[64+c] / M - mean*mean;
    double rstd = 1.0 / sqrt(var + 1e-5);
    double g = (double)inb[IN_G1 + c];
    sc1[u] = (float)(g*rstd);
    sh1[u] = (float)((double)inb[IN_BE1 + c] - mean*g*rstd);
    bb2[u] = inb[IN_B2 + c];
  }
  float s[4] = {0,0,0,0}, s2[4] = {0,0,0,0};
  int base = blockIdx.x * 256;
  for (int it = 0; it < 16; it++){
    unsigned e = (unsigned)(base + it*16 + slot);
    int i = (int)(e / 20u);
    int b = i >> 10;
    int j = idx1[e];
    int gj = (b<<10) + j;
    float4 av = *(const float4*)(a1 + i*64 + cg*4);
    float4 cv = *(const float4*)(c1 + gj*64 + cg*4);
    float4 h;
    h.x = fmaxf(0.f, (av.x+cv.x)*sc1[0] + sh1[0]);
    h.y = fmaxf(0.f, (av.y+cv.y)*sc1[1] + sh1[1]);
    h.z = fmaxf(0.f, (av.z+cv.z)*sc1[2] + sh1[2]);
    h.w = fmaxf(0.f, (av.w+cv.w)*sc1[3] + sh1[3]);
    *(float4*)(buf + slot*68 + cg*4) = h;
    __syncthreads();
    float acc0 = bb2[0], acc1 = bb2[1], acc2 = bb2[2], acc3 = bb2[3];
    const float* bs = buf + slot*68;
    #pragma unroll
    for (int d4 = 0; d4 < 16; d4++){
      float4 hv = *(const float4*)(bs + d4*4);
      float4 w0 = *(const float4*)(W2s + (d4*4+0)*64 + cg*4);
      float4 w1 = *(const float4*)(W2s + (d4*4+1)*64 + cg*4);
      float4 w2 = *(const float4*)(W2s + (d4*4+2)*64 + cg*4);
      float4 w3 = *(const float4*)(W2s + (d4*4+3)*64 + cg*4);
      acc0 += hv.x*w0.x + hv.y*w1.x + hv.z*w2.x + hv.w*w3.x;
      acc1 += hv.x*w0.y + hv.y*w1.y + hv.z*w2.y + hv.w*w3.y;
      acc2 += hv.x*w0.z + hv.y*w1.z + hv.z*w2.z + hv.w*w3.z;
      acc3 += hv.x*w0.w + hv.y*w1.w + hv.z*w2.w + hv.w*w3.w;
    }
    s[0] += acc0; s2[0] += acc0*acc0;
    s[1] += acc1; s2[1] += acc1*acc1;
    s[2] += acc2; s2[2] += acc2*acc2;
    s[3] += acc3; s2[3] += acc3*acc3;
    __syncthreads();
  }
  #pragma unroll
  for (int u = 0; u < 4; u++){
    atomicAdd(&rs[cg*4+u], s[u]);
    atomicAdd(&rs2[cg*4+u], s2[u]);
  }
  __syncthreads();
  if (tid < 64){
    atomicAdd(&stats[128+tid], (double)rs[tid]);
    atomicAdd(&stats[192+tid], (double)rs2[tid]);
  }
}

// ---------------- full MLP1 + max over k -> x1 (slot-stride 68) ----------------
__global__ __launch_bounds__(256) void k_x1(const float* a1, const float* c1,
    const int* idx1, const float* inb, const double* stats, float* x1){
  __shared__ __align__(16) float W2s[4096], W3s[4096];
  __shared__ __align__(16) float buf1[16*68], buf2[16*68];
  __shared__ __align__(16) float red[16*64];
  int tid = threadIdx.x;
  const float* wbuf = inb + IN_WBUF;
  for (int t = tid; t < 4096; t += 256){ W2s[t] = wbuf[WB_W2+t]; W3s[t] = wbuf[WB_W3+t]; }
  int slotid = tid >> 4;
  int n_l = slotid >> 2, eslot = slotid & 3;
  int cg = tid & 15;
  const double M = (double)NEDGE;
  float sc1[4], sh1[4], bb2[4], sc2[4], sh2[4], bb3[4];
  #pragma unroll
  for (int u = 0; u < 4; u++){
    int c = cg*4 + u;
    double m1 = stats[c] / M;
    double v1 = stats[64+c] / M - m1*m1;
    double r1 = 1.0 / sqrt(v1 + 1e-5);
    double gg1 = (double)inb[IN_G1 + c];
    sc1[u] = (float)(gg1*r1);
    sh1[u] = (float)((double)inb[IN_BE1 + c] - m1*gg1*r1);
    bb2[u] = inb[IN_B2 + c];
    double m2 = stats[128+c] / M;
    double v2 = stats[192+c] / M - m2*m2;
    double r2 = 1.0 / sqrt(v2 + 1e-5);
    double gg2 = (double)inb[IN_G2 + c];
    sc2[u] = (float)(gg2*r2);
    sh2[u] = (float)((double)inb[IN_BE2 + c] - m2*gg2*r2);
    bb3[u] = inb[IN_B3 + c];
  }
  __syncthreads();
  int i = blockIdx.x*4 + n_l;
  int b = i >> 10;
  float mx[4] = {-FLT_MAX, -FLT_MAX, -FLT_MAX, -FLT_MAX};
  for (int it = 0; it < 5; it++){
    int kk = it*4 + eslot;
    int j = idx1[i*KNN + kk];
    int gj = (b<<10) + j;
    float4 av = *(const float4*)(a1 + i*64 + cg*4);
    float4 cv = *(const float4*)(c1 + gj*64 + cg*4);
    float4 h;
    h.x = fmaxf(0.f, (av.x+cv.x)*sc1[0] + sh1[0]);
    h.y = fmaxf(0.f, (av.y+cv.y)*sc1[1] + sh1[1]);
    h.z = fmaxf(0.f, (av.z+cv.z)*sc1[2] + sh1[2]);
    h.w = fmaxf(0.f, (av.w+cv.w)*sc1[3] + sh1[3]);
    *(float4*)(buf1 + slotid*68 + cg*4) = h;
    __syncthreads();
    float a0 = bb2[0], a1v = bb2[1], a2v = bb2[2], a3v = bb2[3];
    const float* bs = buf1 + slotid*68;
    #pragma unroll
    for (int d4 = 0; d4 < 16; d4++){
      float4 hv = *(const float4*)(bs + d4*4);
      float4 w0 = *(const float4*)(W2s + (d4*4+0)*64 + cg*4);
      float4 w1 = *(const float4*)(W2s + (d4*4+1)*64 + cg*4);
      float4 w2 = *(const float4*)(W2s + (d4*4+2)*64 + cg*4);
      float4 w3 = *(const float4*)(W2s + (d4*4+3)*64 + cg*4);
      a0  += hv.x*w0.x + hv.y*w1.x + hv.z*w2.x + hv.w*w3.x;
      a1v += hv.x*w0.y + hv.y*w1.y + hv.z*w2.y + hv.w*w3.y;
      a2v += hv.x*w0.z + hv.y*w1.z + hv.z*w2.z + hv.w*w3.z;
      a3v += hv.x*w0.w + hv.y*w1.w + hv.z*w2.w + hv.w*w3.w;
    }
    float4 h2;
    h2.x = fmaxf(0.f, a0*sc2[0] + sh2[0]);
    h2.y = fmaxf(0.f, a1v*sc2[1] + sh2[1]);
    h2.z = fmaxf(0.f, a2v*sc2[2] + sh2[2]);
    h2.w = fmaxf(0.f, a3v*sc2[3] + sh2[3]);
    *(float4*)(buf2 + slotid*68 + cg*4) = h2;
    __syncthreads();
    float c0 = bb3[0], c1v = bb3[1], c2v = bb3[2], c3v = bb3[3];
    const float* bs2 = buf2 + slotid*68;
    #pragma unroll
    for (int d4 = 0; d4 < 16; d4++){
      float4 hv = *(const float4*)(bs2 + d4*4);
      float4 w0 = *(const float4*)(W3s + (d4*4+0)*64 + cg*4);
      float4 w1 = *(const float4*)(W3s + (d4*4+1)*64 + cg*4);
      float4 w2 = *(const float4*)(W3s + (d4*4+2)*64 + cg*4);
      float4 w3 = *(const float4*)(W3s + (d4*4+3)*64 + cg*4);
      c0  += hv.x*w0.x + hv.y*w1.x + hv.z*w2.x + hv.w*w3.x;
      c1v += hv.x*w0.y + hv.y*w1.y + hv.z*w2.y + hv.w*w3.y;
      c2v += hv.x*w0.z + hv.y*w1.z + hv.z*w2.z + hv.w*w3.z;
      c3v += hv.x*w0.w + hv.y*w1.w + hv.z*w2.w + hv.w*w3.w;
    }
    mx[0] = fmaxf(mx[0], c0);  mx[1] = fmaxf(mx[1], c1v);
    mx[2] = fmaxf(mx[2], c2v); mx[3] = fmaxf(mx[3], c3v);
  }
  *(float4*)(red + slotid*64 + cg*4) = make_float4(mx[0], mx[1], mx[2], mx[3]);
  __syncthreads();
  if (eslot == 0){
    #pragma unroll
    for (int u = 0; u < 4; u++){
      int c = cg*4 + u;
      float m = fmaxf(fmaxf(red[(n_l*4+0)*64+c], red[(n_l*4+1)*64+c]),
                      fmaxf(red[(n_l*4+2)*64+c], red[(n_l*4+3)*64+c]));
      x1[i*64 + c] = m;
    }
  }
}

// ---------------- kNN feature space (v8: register unsorted top-20) ----------------
// 64 queries x 4 slots; candidate rows broadcast from LDS; top-20 kept UNSORTED
// in registers with tracked lex-worst (O(1) replace + rescan, pure VALU) ->
// no serial LDS insertion walks. Dump + stream-merge preserves top_k set.
__global__ __launch_bounds__(256, 2) void k_knn2(const float* x1, int* idx2){
  __shared__ __align__(16) float xs[64*68];          // 17408 B
  __shared__ float sqc[64];
  __shared__ float dls[256*21];                      // 21504 B
  __shared__ int   ils[256*21];                      // 21504 B (total ~60 KB)
  int bb = blockIdx.x >> 4;          // batch
  int qg = blockIdx.x & 15;          // query group of 64
  int tid = threadIdx.x;
  int q_l = tid & 63;
  int slot = tid >> 6;               // wave index == slot
  int gi = bb*1024 + qg*64 + q_l;
  float4 xiv[16];
  #pragma unroll
  for (int d4 = 0; d4 < 16; d4++)
    xiv[d4] = *(const float4*)(x1 + gi*64 + d4*4);
  float sqi = 0.f;
  #pragma unroll
  for (int d4 = 0; d4 < 16; d4++)
    sqi += xiv[d4].x*xiv[d4].x + xiv[d4].y*xiv[d4].y
         + xiv[d4].z*xiv[d4].z + xiv[d4].w*xiv[d4].w;
  float rd[KNN]; int ri[KNN];
  #pragma unroll
  for (int p = 0; p < KNN; p++){ rd[p] = FLT_MAX; ri[p] = 65535; }
  float wv = FLT_MAX; int wi = 65535, wpos = 0;
  for (int c0 = 0; c0 < 1024; c0 += 64){
    __syncthreads();
    for (int t = tid; t < 4096; t += 256){
      int r = t >> 6, d = t & 63;
      xs[r*68 + d] = x1[(bb*1024 + c0 + r)*64 + d];
    }
    __syncthreads();
    if (tid < 64){
      float s0 = 0.f, s1 = 0.f;
      #pragma unroll
      for (int d = 0; d < 32; d++){
        s0 += xs[tid*68+d]*xs[tid*68+d];
        s1 += xs[tid*68+32+d]*xs[tid*68+32+d];
      }
      sqc[tid] = s0 + s1;
    }
    __syncthreads();
    for (int u = 0; u < 16; u++){
      int jj = 4*u + slot;
      const float* xr = xs + jj*68;
      float dot0 = 0.f, dot1 = 0.f;
      #pragma unroll
      for (int d4 = 0; d4 < 8; d4++){
        float4 va = *(const float4*)(xr + d4*8);
        float4 vb = *(const float4*)(xr + d4*8 + 4);
        dot0 += xiv[2*d4].x*va.x + xiv[2*d4].y*va.y + xiv[2*d4].z*va.z + xiv[2*d4].w*va.w;
        dot1 += xiv[2*d4+1].x*vb.x + xiv[2*d4+1].y*vb.y + xiv[2*d4+1].z*vb.z + xiv[2*d4+1].w*vb.w;
      }
      float d = sqi + sqc[jj] - 2.0f*(dot0 + dot1);
      KNN_INS(d, c0 + jj)
    }
  }
  __syncthreads();
  int base = tid*21;
  #pragma unroll
  for (int p = 0; p < KNN; p++){ dls[base+p] = rd[p]; ils[base+p] = ri[p]; }
  __syncthreads();
  if (slot == 0){
    for (int s = 1; s < 4; s++){
      int sb = (s*64 + q_l)*21;
      for (int p = 0; p < KNN; p++){
        float d = dls[sb+p];
        int ci = ils[sb+p];
        KNN_INS(d, ci)
      }
    }
    #pragma unroll
    for (int p = 0; p < KNN; p++) idx2[gi*KNN+p] = ri[p];   // unsorted set
  }
}

// ---------------- fast path: B2H = x1 @ Wbot[:, q-half] ----------------
__global__ __launch_bounds__(256) void k_B2h(const float* x1, const float* inb,
                                             int q, float* B2H){
  __shared__ __align__(16) float Wbh[4096];
  __shared__ __align__(16) float xsh[1024];
  int tid = threadIdx.x;
  const float* Wb = inb + IN_WBUF + WB_WBOT;
  for (int t = tid; t < 4096; t += 256){
    int r = t >> 6, cl = t & 63;
    Wbh[t] = Wb[r*128 + q*64 + cl];
  }
  int node0 = blockIdx.x * 16;
  for (int t = tid; t < 1024; t += 256) xsh[t] = x1[node0*64 + t];
  __syncthreads();
  int n_l = tid >> 4, cg = tid & 15;
  const float* xr = xsh + n_l*64;
  float4 acc = make_float4(0.f,0.f,0.f,0.f);
  #pragma unroll 8
  for (int d = 0; d < 64; d++){
    float v = xr[d];
    float4 w = *(const float4*)(Wbh + d*64 + cg*4);
    acc.x += v*w.x; acc.y += v*w.y; acc.z += v*w.z; acc.w += v*w.w;
  }
  *(float4*)(B2H + (node0 + n_l)*64 + cg*4) = acc;
}

// ---------------- fast path: x2 half = (x1_i@Wd + bc2) + max_j B2H[j] ----------------
__global__ __launch_bounds__(256) void k_x2h(const float* x1, const float* B2H,
                                             const float* inb, const int* idx2,
                                             int q, float* x2){
  __shared__ __align__(16) float Wdh[4096];
  __shared__ __align__(16) float xsh[256];
  int tid = threadIdx.x;
  const float* Wd = inb + IN_WBUF + WB_WD;
  for (int t = tid; t < 4096; t += 256){
    int r = t >> 6, cl = t & 63;
    Wdh[t] = Wd[r*128 + q*64 + cl];
  }
  int node0 = blockIdx.x * 4;
  xsh[tid] = x1[node0*64 + tid];
  __syncthreads();
  int n_l = tid >> 6, cl = tid & 63;
  int i = node0 + n_l;
  int b = i >> 10;
  const float* xr = xsh + n_l*64;
  float acc = inb[IN_BC2 + q*64 + cl];
  #pragma unroll 8
  for (int d = 0; d < 64; d++) acc += xr[d]*Wdh[d*64 + cl];
  float m = -FLT_MAX;
  for (int kk = 0; kk < KNN; kk++){
    int j = idx2[i*KNN + kk];
    m = fmaxf(m, B2H[((b<<10)+j)*64 + cl]);
  }
  x2[i*128 + q*64 + cl] = acc + m;
}

// ---------------- slow fallback: x2 direct, LDS-staged, no B2H buffer ----------------
__global__ __launch_bounds__(256) void k_x2d(const float* x1, const float* inb,
                                             const int* idx2, float* x2){
  __shared__ __align__(16) float Wdh[4096], Wbh[4096];
  __shared__ __align__(16) float xis[1024], xjs[1024];
  int tid = threadIdx.x;
  int q = blockIdx.x & 1;
  int node0 = (blockIdx.x >> 1) * 16;
  const float* Wd = inb + IN_WBUF + WB_WD;
  const float* Wb = inb + IN_WBUF + WB_WBOT;
  for (int t = tid; t < 4096; t += 256){
    int r = t >> 6, cl = t & 63;
    Wdh[t] = Wd[r*128 + q*64 + cl];
    Wbh[t] = Wb[r*128 + q*64 + cl];
  }
  for (int t = tid; t < 1024; t += 256) xis[t] = x1[node0*64 + t];
  __syncthreads();
  int n_l = tid >> 4, cg = tid & 15;
  int i = node0 + n_l, b = i >> 10;
  const float* xr = xis + n_l*64;
  float4 af = make_float4(inb[IN_BC2 + q*64 + cg*4],   inb[IN_BC2 + q*64 + cg*4+1],
                          inb[IN_BC2 + q*64 + cg*4+2], inb[IN_BC2 + q*64 + cg*4+3]);
  #pragma unroll 8
  for (int d = 0; d < 64; d++){
    float v = xr[d];
    float4 w = *(const float4*)(Wdh + d*64 + cg*4);
    af.x += v*w.x; af.y += v*w.y; af.z += v*w.z; af.w += v*w.w;
  }
  float4 mx = make_float4(-FLT_MAX,-FLT_MAX,-FLT_MAX,-FLT_MAX);
  for (int kk = 0; kk < KNN; kk++){
    __syncthreads();
    for (int t = tid; t < 1024; t += 256){
      int nn = t >> 6, r = t & 63;
      int jj = idx2[(node0+nn)*KNN + kk];
      xjs[t] = x1[((((node0+nn) >> 10) << 10) + jj)*64 + r];
    }
    __syncthreads();
    const float* xj = xjs + n_l*64;
    float4 acc = make_float4(0.f,0.f,0.f,0.f);
    #pragma unroll 8
    for (int d = 0; d < 64; d++){
      float v = xj[d];
      float4 w = *(const float4*)(Wbh + d*64 + cg*4);
      acc.x += v*w.x; acc.y += v*w.y; acc.z += v*w.z; acc.w += v*w.w;
    }
    mx.x = fmaxf(mx.x, acc.x); mx.y = fmaxf(mx.y, acc.y);
    mx.z = fmaxf(mx.z, acc.z); mx.w = fmaxf(mx.w, acc.w);
  }
  *(float4*)(x2 + i*128 + q*64 + cg*4) =
      make_float4(af.x+mx.x, af.y+mx.y, af.z+mx.z, af.w+mx.w);
}

// ---------------- lin (192->1024) + partial max over n-quarter ----------------
__global__ __launch_bounds__(256) void k_linpool(const float* x1, const float* x2,
    const float* inb, float* pool4){
  __shared__ __align__(16) float fst[192*36];
  __shared__ float red2[1024];
  int tid = threadIdx.x;
  int b = blockIdx.x >> 4, cq = (blockIdx.x >> 2) & 3, nh = blockIdx.x & 3;
  int cg = tid & 63, n8 = tid >> 6;
  int cbase = cq*256 + cg*4;
  const float* Wl = inb + IN_WBUF + WB_WL;
  float m0 = -FLT_MAX, m1 = -FLT_MAX, m2 = -FLT_MAX, m3 = -FLT_MAX;
  for (int ng = 0; ng < 8; ng++){
    __syncthreads();
    for (int t = tid; t < 6144; t += 256){
      int n_l = t / 192, dd = t - n_l*192;
      int gi = b*1024 + nh*256 + ng*32 + n_l;
      fst[dd*36 + n_l] = (dd < 64) ? x1[gi*64 + dd] : x2[gi*128 + dd - 64];
    }
    __syncthreads();
    float acc[8][4];
    #pragma unroll
    for (int n = 0; n < 8; n++){ acc[n][0]=0; acc[n][1]=0; acc[n][2]=0; acc[n][3]=0; }
    #pragma unroll 4
    for (int d = 0; d < 192; d++){
      float4 w = *(const float4*)(Wl + d*1024 + cbase);
      const float* fr = fst + d*36 + n8*8;
      float4 f0 = *(const float4*)(fr);
      float4 f1 = *(const float4*)(fr + 4);
      float fv[8] = {f0.x, f0.y, f0.z, f0.w, f1.x, f1.y, f1.z, f1.w};
      #pragma unroll
      for (int n = 0; n < 8; n++){
        acc[n][0] += fv[n]*w.x; acc[n][1] += fv[n]*w.y;
        acc[n][2] += fv[n]*w.z; acc[n][3] += fv[n]*w.w;
      }
    }
    #pragma unroll
    for (int n = 0; n < 8; n++){
      m0 = fmaxf(m0, acc[n][0]); m1 = fmaxf(m1, acc[n][1]);
      m2 = fmaxf(m2, acc[n][2]); m3 = fmaxf(m3, acc[n][3]);
    }
  }
  red2[n8*256 + cg*4]   = m0;  red2[n8*256 + cg*4+1] = m1;
  red2[n8*256 + cg*4+2] = m2;  red2[n8*256 + cg*4+3] = m3;
  __syncthreads();
  if (n8 == 0){
    #pragma unroll
    for (int u = 0; u < 4; u++){
      int cc = cg*4 + u;
      float m = fmaxf(fmaxf(red2[cc], red2[256+cc]), fmaxf(red2[512+cc], red2[768+cc]));
      pool4[nh*32768 + b*1024 + cbase + u] = m;     // bias applied in k_head
    }
  }
}

// ---------------- head MLP: reduce pool4 + 1024->512->256->40 (fp32 out) ----------------
__global__ __launch_bounds__(256) void k_head(const float* pool4, const float* inb,
                                              float* out){
  __shared__ float pl[1024];
  __shared__ float s1[512];
  __shared__ float s2[256];
  int b = blockIdx.x, tid = threadIdx.x;
  const float* Wm1 = inb + IN_WBUF + WB_WM1;
  const float* Wm2 = inb + IN_WBUF + WB_WM2;
  const float* Wm3 = inb + IN_WBUF + WB_WM3;
  for (int t = tid; t < 1024; t += 256){
    float m = fmaxf(fmaxf(pool4[b*1024 + t],         pool4[32768 + b*1024 + t]),
                    fmaxf(pool4[65536 + b*1024 + t], pool4[98304 + b*1024 + t]));
    pl[t] = m + inb[IN_BL + t];
  }
  __syncthreads();
  for (int c = tid; c < 512; c += 256){
    float acc = inb[IN_BM1 + c];
    #pragma unroll 4
    for (int d = 0; d < 1024; d++) acc += pl[d]*Wm1[d*512 + c];
    s1[c] = fmaxf(acc, 0.f);
  }
  __syncthreads();
  {
    int c = tid;
    float acc = inb[IN_BM2 + c];
    #pragma unroll 4
    for (int d = 0; d < 512; d++) acc += s1[d]*Wm2[d*256 + c];
    s2[c] = fmaxf(acc, 0.f);
  }
  __syncthreads();
  if (tid < 40){
    float acc = inb[IN_BM3 + tid];
    #pragma unroll 4
    for (int d = 0; d < 256; d++) acc += s2[d]*Wm3[d*40 + tid];
    out[b*40 + tid] = acc;
  }
}

extern "C" void kernel_launch(void* const* d_in, const int* in_sizes, int n_in,
                              void* d_out, int out_size, void* d_ws, size_t ws_size,
                              hipStream_t stream){
  float* ws     = (float*)d_ws;
  double* stats = (double*)d_ws;
  int*   flag   = (int*)d_ws + OFF_FLAG;
  float* inb    = ws + OFF_INB;
  int*   idx    = (int*)d_ws + OFF_IDX;     // idx1 early, idx2 late
  float* x1p    = ws + OFF_X1;
  float* x2p    = ws + OFF_X2;
  float* a1     = ws + OFF_X2;              // a1/c1 alias x2 region (dead before x2 written)
  float* c1     = ws + OFF_C1;
  float* pool4  = ws + OFF_POOL;
  float* B2H    = ws + OFF_B2H;
  bool fast = ws_size >= (size_t)FAST_END * 4u;

  hipMemsetAsync(stats, 0, 256*sizeof(double), stream);
  k_sniff<<<1, 64, 0, stream>>>(d_in[0], flag);
  k_cvt<<<3859, 256, 0, stream>>>(
      d_in[0], d_in[1], d_in[2], d_in[3], d_in[4], d_in[5], d_in[6], d_in[7],
      d_in[8], d_in[9], d_in[10], d_in[11], d_in[12], d_in[13], d_in[14],
      d_in[15], d_in[16], d_in[17], d_in[18], d_in[19], d_in[20], flag, inb);
  k_prep1<<<8192, 256, 0, stream>>>(inb, a1, c1);
  k_knn1<<<512, 256, 0, stream>>>(inb, idx);
  k_stats1<<<640, 256, 0, stream>>>(a1, c1, idx, stats);
  k_stats2<<<2560, 256, 0, stream>>>(a1, c1, idx, inb, stats);
  k_x1<<<8192, 256, 0, stream>>>(a1, c1, idx, inb, stats, x1p);
  k_knn2<<<512, 256, 0, stream>>>(x1p, idx);
  if (fast){
    k_B2h<<<2048, 256, 0, stream>>>(x1p, inb, 0, B2H);
    k_x2h<<<8192, 256, 0, stream>>>(x1p, B2H, inb, idx, 0, x2p);
    k_B2h<<<2048, 256, 0, stream>>>(x1p, inb, 1, B2H);
    k_x2h<<<8192, 256, 0, stream>>>(x1p, B2H, inb, idx, 1, x2p);
  } else {
    k_x2d<<<4096, 256, 0, stream>>>(x1p, inb, idx, x2p);
  }
  k_linpool<<<512, 256, 0, stream>>>(x1p, x2p, inb, pool4);
  k_head<<<32, 256, 0, stream>>>(pool4, inb, (float*)d_out);
}

// Round 15
// 1849.432 us; speedup vs baseline: 1.1287x; 1.1287x over previous
//
#include <hip/hip_runtime.h>
#include <hip/hip_bf16.h>
#include <float.h>
#include <math.h>

typedef __hip_bfloat16 bf16;

#define BATCH 32
#define NPTS  1024
#define KNN   20
#define NB    (BATCH*NPTS)      // 32768 nodes
#define NEDGE (NB*KNN)          // 655360 edges

// ---- workspace layout (float units), ws_size-adaptive ----
#define OFF_FLAG 512u
#define OFF_INB  1024u
#define OFF_IDX  988928u          // 655360 ints (idx1 early, idx2 late)
#define OFF_X1   1644288u         // NB*64
#define OFF_X2   3741440u         // NB*128 ; a1 @ OFF_X2, c1 @ OFF_C1 (early)
#define OFF_C1   5838592u
#define OFF_POOL 7935744u         // pool4: 4 x 32*1024
#define SLOW_END 8066816u         // 32.3 MB
#define OFF_B2H  8066816u         // NB*64 (fast path only)
#define FAST_END 10163968u        // 40.7 MB
// ---- layout inside inb (canonical fp32 inputs) ----
#define IN_POSF 0u
#define IN_B1   98304u
#define IN_G1   98368u
#define IN_BE1  98432u
#define IN_B2   98496u
#define IN_G2   98560u
#define IN_BE2  98624u
#define IN_B3   98688u
#define IN_BC2  98752u
#define IN_BL   98880u
#define IN_BM1  99904u
#define IN_BM2  100416u
#define IN_BM3  100672u
#define IN_W1   100736u
#define IN_WBUF 101120u
#define WB_W2   0u
#define WB_W3   4096u
#define WB_WD   8192u            // Wc2 top-bot diff [64x128]
#define WB_WBOT 16384u           // Wc2 bottom      [64x128]
#define WB_WL   24576u
#define WB_WM1  221184u
#define WB_WM2  745472u
#define WB_WM3  876544u
#define IN_TOTAL 987904u

__device__ __forceinline__ float bf2f(bf16 v){ return __bfloat162float(v); }

// ---------------- dtype sniff (fp32 vs bf16 inputs) ----------------
__global__ void k_sniff(const void* pos_raw, int* flag){
  if (blockIdx.x == 0 && threadIdx.x == 0){
    const unsigned short* h = (const unsigned short*)pos_raw;
    int wild = 0;
    for (int k = 0; k < 16; k++){
      unsigned int bits = ((unsigned int)h[2*k]) << 16;
      float v = __uint_as_float(bits);
      float a = fabsf(v);
      if (a != 0.0f && (v != v || a > 1e10f || a < 1e-10f)) wild++;
    }
    *flag = (wild >= 4) ? 1 : 0;
  }
}

__device__ __forceinline__ float rdv(const void* p, int i, int f){
  return f ? ((const float*)p)[i] : bf2f(((const bf16*)p)[i]);
}

// ---------------- normalize ALL inputs to canonical fp32 buffer ----------------
__global__ __launch_bounds__(256) void k_cvt(
    const void* pos, const void* W1, const void* b1, const void* g1, const void* be1,
    const void* W2, const void* b2, const void* g2, const void* be2,
    const void* W3, const void* b3, const void* Wc2, const void* bc2,
    const void* Wl, const void* bl, const void* Wm1, const void* bm1,
    const void* Wm2, const void* bm2, const void* Wm3, const void* bm3,
    const int* flag, float* inb){
  int id = blockIdx.x*256 + threadIdx.x;
  if (id >= (int)IN_TOTAL) return;
  int f = *flag;
  float v;
  if      (id < 98304)  v = rdv(pos, id, f);
  else if (id < 98368)  v = rdv(b1,  id-98304, f);
  else if (id < 98432)  v = rdv(g1,  id-98368, f);
  else if (id < 98496)  v = rdv(be1, id-98432, f);
  else if (id < 98560)  v = rdv(b2,  id-98496, f);
  else if (id < 98624)  v = rdv(g2,  id-98560, f);
  else if (id < 98688)  v = rdv(be2, id-98624, f);
  else if (id < 98752)  v = rdv(b3,  id-98688, f);
  else if (id < 98880)  v = rdv(bc2, id-98752, f);
  else if (id < 99904)  v = rdv(bl,  id-98880, f);
  else if (id < 100416) v = rdv(bm1, id-99904, f);
  else if (id < 100672) v = rdv(bm2, id-100416, f);
  else if (id < 100712) v = rdv(bm3, id-100672, f);
  else if (id < 100736) v = 0.0f;
  else if (id < 101120) v = rdv(W1,  id-100736, f);
  else {
    int t = id - 101120;
    if      (t < 4096)   v = rdv(W2, t, f);
    else if (t < 8192)   v = rdv(W3, t-4096, f);
    else if (t < 16384){ int u = t-8192;  v = rdv(Wc2, u, f) - rdv(Wc2, 8192+u, f); }
    else if (t < 24576){ int u = t-16384; v = rdv(Wc2, 8192+u, f); }
    else if (t < 221184) v = rdv(Wl,  t-24576, f);
    else if (t < 745472) v = rdv(Wm1, t-221184, f);
    else if (t < 876544) v = rdv(Wm2, t-745472, f);
    else                 v = rdv(Wm3, t-876544, f);
  }
  inb[id] = v;
}

// ---------------- a1/c1: affine decomposition of EdgeConv1 layer1 ----------------
__global__ __launch_bounds__(256) void k_prep1(const float* inb, float* a1, float* c1){
  const float* posf = inb + IN_POSF;
  const float* W1f  = inb + IN_W1;
  const float* b1f  = inb + IN_B1;
  int id = blockIdx.x*256 + threadIdx.x;
  int bn = id >> 6, c = id & 63;
  float p0 = posf[bn*3], p1 = posf[bn*3+1], p2 = posf[bn*3+2];
  float wt0 = W1f[c],     wt1 = W1f[64+c],  wt2 = W1f[128+c];
  float wb0 = W1f[192+c], wb1 = W1f[256+c], wb2 = W1f[320+c];
  float cv = p0*wb0 + p1*wb1 + p2*wb2;
  float av = p0*(wt0-wb0) + p1*(wt1-wb1) + p2*(wt2-wb2) + b1f[c];
  a1[id] = av;  c1[id] = cv;
}

// ---------------- kNN in coordinate space (high-occupancy split-scan) ----------------
__global__ __launch_bounds__(256, 3) void k_knn1(const float* inb, int* idx1){
  const float* posf = inb + IN_POSF;
  __shared__ float psx[1024], psy[1024], psz[1024], sqs[1024];
  __shared__ float dl[256*21];
  __shared__ unsigned short il[256*21];
  int bb = blockIdx.x >> 4;
  int qg = blockIdx.x & 15;
  int tid = threadIdx.x;
  int q_l = tid & 63;
  int slot = tid >> 6;
  for (int t = tid; t < 1024; t += 256){
    float x = posf[(bb*1024+t)*3], y = posf[(bb*1024+t)*3+1], z = posf[(bb*1024+t)*3+2];
    psx[t] = x; psy[t] = y; psz[t] = z; sqs[t] = x*x + y*y + z*z;
  }
  __syncthreads();
  int i_l = qg*64 + q_l;
  float xi0 = psx[i_l], xi1 = psy[i_l], xi2 = psz[i_l];
  float sqi = sqs[i_l];
  int base = tid*21;
  for (int p = 0; p < KNN; p++){ dl[base+p] = FLT_MAX; il[base+p] = 65535; }
  float t19d = FLT_MAX;
  for (int u = 0; u < 256; u++){
    int jj = 4*u + slot;
    float dot = xi0*psx[jj] + xi1*psy[jj] + xi2*psz[jj];
    float d = sqi + sqs[jj] - 2.0f*dot;
    if (d < t19d){
      int p = KNN-1;
      while (p > 0 && dl[base+p-1] > d){
        dl[base+p] = dl[base+p-1]; il[base+p] = il[base+p-1]; p--;
      }
      dl[base+p] = d; il[base+p] = (unsigned short)jj;
      t19d = dl[base+KNN-1];
    }
  }
  __syncthreads();
  if (slot == 0){
    int mb = tid*21;
    for (int s = 1; s < 4; s++){
      int sb = (s*64 + q_l)*21;
      for (int p = 0; p < KNN; p++){
        float d = dl[sb+p];
        unsigned short ci = il[sb+p];
        float fd = dl[mb+KNN-1];
        unsigned short fi = il[mb+KNN-1];
        if (d > fd || (d == fd && ci > fi)) break;
        int q = KNN-1;
        while (q > 0 && (dl[mb+q-1] > d ||
               (dl[mb+q-1] == d && il[mb+q-1] > ci))){
          dl[mb+q] = dl[mb+q-1]; il[mb+q] = il[mb+q-1]; q--;
        }
        dl[mb+q] = d; il[mb+q] = ci;
      }
    }
    int gi = bb*1024 + i_l;
    for (int p = 0; p < KNN; p++) idx1[gi*KNN+p] = (int)il[mb+p];
  }
}

// ---------------- BN1 stats ----------------
__global__ __launch_bounds__(256) void k_stats1(const float* a1, const float* c1,
                                                const int* idx1, double* stats){
  __shared__ float rs[256], rs2[256];
  int tid = threadIdx.x, c = tid & 63, slot = tid >> 6;
  int base = blockIdx.x * 1024;
  float s = 0.f, s2 = 0.f;
  for (int t = 0; t < 256; t++){
    unsigned e = (unsigned)(base + t*4 + slot);
    int i = (int)(e / 20u);
    int b = i >> 10;
    int j = idx1[e];
    float h = a1[i*64+c] + c1[((b<<10)+j)*64 + c];
    s += h; s2 += h*h;
  }
  rs[tid] = s; rs2[tid] = s2;
  __syncthreads();
  if (slot == 0){
    double ts  = (double)rs[c]  + (double)rs[64+c]  + (double)rs[128+c]  + (double)rs[192+c];
    double ts2 = (double)rs2[c] + (double)rs2[64+c] + (double)rs2[128+c] + (double)rs2[192+c];
    atomicAdd(&stats[c], ts);
    atomicAdd(&stats[64+c], ts2);
  }
}

// ---------------- BN2 stats (slot-stride 68: bank-conflict-free) ----------------
__global__ __launch_bounds__(256) void k_stats2(const float* a1, const float* c1,
    const int* idx1, const float* inb, double* stats){
  __shared__ __align__(16) float W2s[4096];
  __shared__ __align__(16) float buf[16*68];
  __shared__ float rs[64], rs2[64];
  int tid = threadIdx.x;
  const float* wbuf = inb + IN_WBUF;
  for (int t = tid; t < 4096; t += 256) W2s[t] = wbuf[WB_W2 + t];
  if (tid < 64){ rs[tid] = 0.f; rs2[tid] = 0.f; }
  int slot = tid >> 4;
  int cg = tid & 15;
  const double M = (double)NEDGE;
  float sc1[4], sh1[4], bb2[4];
  #pragma unroll
  for (int u = 0; u < 4; u++){
    int c = cg*4 + u;
    double mean = stats[c] / M;
    double var  = stats[64+c] / M - mean*mean;
    double rstd = 1.0 / sqrt(var + 1e-5);
    double g = (double)inb[IN_G1 + c];
    sc1[u] = (float)(g*rstd);
    sh1[u] = (float)((double)inb[IN_BE1 + c] - mean*g*rstd);
    bb2[u] = inb[IN_B2 + c];
  }
  float s[4] = {0,0,0,0}, s2[4] = {0,0,0,0};
  int base = blockIdx.x * 256;
  for (int it = 0; it < 16; it++){
    unsigned e = (unsigned)(base + it*16 + slot);
    int i = (int)(e / 20u);
    int b = i >> 10;
    int j = idx1[e];
    int gj = (b<<10) + j;
    float4 av = *(const float4*)(a1 + i*64 + cg*4);
    float4 cv = *(const float4*)(c1 + gj*64 + cg*4);
    float4 h;
    h.x = fmaxf(0.f, (av.x+cv.x)*sc1[0] + sh1[0]);
    h.y = fmaxf(0.f, (av.y+cv.y)*sc1[1] + sh1[1]);
    h.z = fmaxf(0.f, (av.z+cv.z)*sc1[2] + sh1[2]);
    h.w = fmaxf(0.f, (av.w+cv.w)*sc1[3] + sh1[3]);
    *(float4*)(buf + slot*68 + cg*4) = h;
    __syncthreads();
    float acc0 = bb2[0], acc1 = bb2[1], acc2 = bb2[2], acc3 = bb2[3];
    const float* bs = buf + slot*68;
    #pragma unroll
    for (int d4 = 0; d4 < 16; d4++){
      float4 hv = *(const float4*)(bs + d4*4);
      float4 w0 = *(const float4*)(W2s + (d4*4+0)*64 + cg*4);
      float4 w1 = *(const float4*)(W2s + (d4*4+1)*64 + cg*4);
      float4 w2 = *(const float4*)(W2s + (d4*4+2)*64 + cg*4);
      float4 w3 = *(const float4*)(W2s + (d4*4+3)*64 + cg*4);
      acc0 += hv.x*w0.x + hv.y*w1.x + hv.z*w2.x + hv.w*w3.x;
      acc1 += hv.x*w0.y + hv.y*w1.y + hv.z*w2.y + hv.w*w3.y;
      acc2 += hv.x*w0.z + hv.y*w1.z + hv.z*w2.z + hv.w*w3.z;
      acc3 += hv.x*w0.w + hv.y*w1.w + hv.z*w2.w + hv.w*w3.w;
    }
    s[0] += acc0; s2[0] += acc0*acc0;
    s[1] += acc1; s2[1] += acc1*acc1;
    s[2] += acc2; s2[2] += acc2*acc2;
    s[3] += acc3; s2[3] += acc3*acc3;
    __syncthreads();
  }
  #pragma unroll
  for (int u = 0; u < 4; u++){
    atomicAdd(&rs[cg*4+u], s[u]);
    atomicAdd(&rs2[cg*4+u], s2[u]);
  }
  __syncthreads();
  if (tid < 64){
    atomicAdd(&stats[128+tid], (double)rs[tid]);
    atomicAdd(&stats[192+tid], (double)rs2[tid]);
  }
}

// ---------------- full MLP1 + max over k -> x1 (slot-stride 68) ----------------
__global__ __launch_bounds__(256) void k_x1(const float* a1, const float* c1,
    const int* idx1, const float* inb, const double* stats, float* x1){
  __shared__ __align__(16) float W2s[4096], W3s[4096];
  __shared__ __align__(16) float buf1[16*68], buf2[16*68];
  __shared__ __align__(16) float red[16*64];
  int tid = threadIdx.x;
  const float* wbuf = inb + IN_WBUF;
  for (int t = tid; t < 4096; t += 256){ W2s[t] = wbuf[WB_W2+t]; W3s[t] = wbuf[WB_W3+t]; }
  int slotid = tid >> 4;
  int n_l = slotid >> 2, eslot = slotid & 3;
  int cg = tid & 15;
  const double M = (double)NEDGE;
  float sc1[4], sh1[4], bb2[4], sc2[4], sh2[4], bb3[4];
  #pragma unroll
  for (int u = 0; u < 4; u++){
    int c = cg*4 + u;
    double m1 = stats[c] / M;
    double v1 = stats[64+c] / M - m1*m1;
    double r1 = 1.0 / sqrt(v1 + 1e-5);
    double gg1 = (double)inb[IN_G1 + c];
    sc1[u] = (float)(gg1*r1);
    sh1[u] = (float)((double)inb[IN_BE1 + c] - m1*gg1*r1);
    bb2[u] = inb[IN_B2 + c];
    double m2 = stats[128+c] / M;
    double v2 = stats[192+c] / M - m2*m2;
    double r2 = 1.0 / sqrt(v2 + 1e-5);
    double gg2 = (double)inb[IN_G2 + c];
    sc2[u] = (float)(gg2*r2);
    sh2[u] = (float)((double)inb[IN_BE2 + c] - m2*gg2*r2);
    bb3[u] = inb[IN_B3 + c];
  }
  __syncthreads();
  int i = blockIdx.x*4 + n_l;
  int b = i >> 10;
  float mx[4] = {-FLT_MAX, -FLT_MAX, -FLT_MAX, -FLT_MAX};
  for (int it = 0; it < 5; it++){
    int kk = it*4 + eslot;
    int j = idx1[i*KNN + kk];
    int gj = (b<<10) + j;
    float4 av = *(const float4*)(a1 + i*64 + cg*4);
    float4 cv = *(const float4*)(c1 + gj*64 + cg*4);
    float4 h;
    h.x = fmaxf(0.f, (av.x+cv.x)*sc1[0] + sh1[0]);
    h.y = fmaxf(0.f, (av.y+cv.y)*sc1[1] + sh1[1]);
    h.z = fmaxf(0.f, (av.z+cv.z)*sc1[2] + sh1[2]);
    h.w = fmaxf(0.f, (av.w+cv.w)*sc1[3] + sh1[3]);
    *(float4*)(buf1 + slotid*68 + cg*4) = h;
    __syncthreads();
    float a0 = bb2[0], a1v = bb2[1], a2v = bb2[2], a3v = bb2[3];
    const float* bs = buf1 + slotid*68;
    #pragma unroll
    for (int d4 = 0; d4 < 16; d4++){
      float4 hv = *(const float4*)(bs + d4*4);
      float4 w0 = *(const float4*)(W2s + (d4*4+0)*64 + cg*4);
      float4 w1 = *(const float4*)(W2s + (d4*4+1)*64 + cg*4);
      float4 w2 = *(const float4*)(W2s + (d4*4+2)*64 + cg*4);
      float4 w3 = *(const float4*)(W2s + (d4*4+3)*64 + cg*4);
      a0  += hv.x*w0.x + hv.y*w1.x + hv.z*w2.x + hv.w*w3.x;
      a1v += hv.x*w0.y + hv.y*w1.y + hv.z*w2.y + hv.w*w3.y;
      a2v += hv.x*w0.z + hv.y*w1.z + hv.z*w2.z + hv.w*w3.z;
      a3v += hv.x*w0.w + hv.y*w1.w + hv.z*w2.w + hv.w*w3.w;
    }
    float4 h2;
    h2.x = fmaxf(0.f, a0*sc2[0] + sh2[0]);
    h2.y = fmaxf(0.f, a1v*sc2[1] + sh2[1]);
    h2.z = fmaxf(0.f, a2v*sc2[2] + sh2[2]);
    h2.w = fmaxf(0.f, a3v*sc2[3] + sh2[3]);
    *(float4*)(buf2 + slotid*68 + cg*4) = h2;
    __syncthreads();
    float c0 = bb3[0], c1v = bb3[1], c2v = bb3[2], c3v = bb3[3];
    const float* bs2 = buf2 + slotid*68;
    #pragma unroll
    for (int d4 = 0; d4 < 16; d4++){
      float4 hv = *(const float4*)(bs2 + d4*4);
      float4 w0 = *(const float4*)(W3s + (d4*4+0)*64 + cg*4);
      float4 w1 = *(const float4*)(W3s + (d4*4+1)*64 + cg*4);
      float4 w2 = *(const float4*)(W3s + (d4*4+2)*64 + cg*4);
      float4 w3 = *(const float4*)(W3s + (d4*4+3)*64 + cg*4);
      c0  += hv.x*w0.x + hv.y*w1.x + hv.z*w2.x + hv.w*w3.x;
      c1v += hv.x*w0.y + hv.y*w1.y + hv.z*w2.y + hv.w*w3.y;
      c2v += hv.x*w0.z + hv.y*w1.z + hv.z*w2.z + hv.w*w3.z;
      c3v += hv.x*w0.w + hv.y*w1.w + hv.z*w2.w + hv.w*w3.w;
    }
    mx[0] = fmaxf(mx[0], c0);  mx[1] = fmaxf(mx[1], c1v);
    mx[2] = fmaxf(mx[2], c2v); mx[3] = fmaxf(mx[3], c3v);
  }
  *(float4*)(red + slotid*64 + cg*4) = make_float4(mx[0], mx[1], mx[2], mx[3]);
  __syncthreads();
  if (eslot == 0){
    #pragma unroll
    for (int u = 0; u < 4; u++){
      int c = cg*4 + u;
      float m = fmaxf(fmaxf(red[(n_l*4+0)*64+c], red[(n_l*4+1)*64+c]),
                      fmaxf(red[(n_l*4+2)*64+c], red[(n_l*4+3)*64+c]));
      x1[i*64 + c] = m;
    }
  }
}

// ---------------- kNN in 64-d feature space (v9: v6 + 2-candidate ILP) ----------------
// Round-12 v6 structure (64 queries x 4 slots, broadcast reads, stride-21 lists,
// register threshold). Scan processes 2 candidates per iteration: both dots
// issue before either gated insert -> ILP to hide the insert walk latency.
// Insert order stays ascending jj per slot -> identical top_k tie semantics.
__global__ __launch_bounds__(256, 3) void k_knn2(const float* x1, int* idx2){
  __shared__ __align__(16) float xs[64*68];          // 17408 B
  __shared__ float sqc[64];
  __shared__ float dl[256*21];                       // 21504 B
  __shared__ unsigned short il[256*21];              // 10752 B (total 49.9 KB)
  int bb = blockIdx.x >> 4;          // batch
  int qg = blockIdx.x & 15;          // query group of 64
  int tid = threadIdx.x;
  int q_l = tid & 63;
  int slot = tid >> 6;               // wave index == slot
  int gi = bb*1024 + qg*64 + q_l;
  float4 xiv[16];
  #pragma unroll
  for (int d4 = 0; d4 < 16; d4++)
    xiv[d4] = *(const float4*)(x1 + gi*64 + d4*4);
  float sqi = 0.f;
  #pragma unroll
  for (int d4 = 0; d4 < 16; d4++)
    sqi += xiv[d4].x*xiv[d4].x + xiv[d4].y*xiv[d4].y
         + xiv[d4].z*xiv[d4].z + xiv[d4].w*xiv[d4].w;
  int base = tid*21;
  for (int p = 0; p < KNN; p++){ dl[base+p] = FLT_MAX; il[base+p] = 65535; }
  float t19d = FLT_MAX;
  for (int c0 = 0; c0 < 1024; c0 += 64){
    __syncthreads();
    for (int t = tid; t < 4096; t += 256){
      int r = t >> 6, d = t & 63;
      xs[r*68 + d] = x1[(bb*1024 + c0 + r)*64 + d];
    }
    __syncthreads();
    if (tid < 64){
      float s = 0.f;
      #pragma unroll 16
      for (int d = 0; d < 64; d++) s += xs[tid*68+d]*xs[tid*68+d];
      sqc[tid] = s;
    }
    __syncthreads();
    for (int u = 0; u < 16; u += 2){
      int jj0 = 4*u + slot;
      int jj1 = 4*(u+1) + slot;
      const float* xr0 = xs + jj0*68;
      const float* xr1 = xs + jj1*68;
      float dot0 = 0.f, dot1 = 0.f;
      #pragma unroll
      for (int d4 = 0; d4 < 16; d4++){
        float4 v0 = *(const float4*)(xr0 + d4*4);
        float4 v1 = *(const float4*)(xr1 + d4*4);
        dot0 += xiv[d4].x*v0.x + xiv[d4].y*v0.y + xiv[d4].z*v0.z + xiv[d4].w*v0.w;
        dot1 += xiv[d4].x*v1.x + xiv[d4].y*v1.y + xiv[d4].z*v1.z + xiv[d4].w*v1.w;
      }
      float d0 = sqi + sqc[jj0] - 2.0f*dot0;
      float d1 = sqi + sqc[jj1] - 2.0f*dot1;
      if (d0 < t19d){      // ascending per-slot scan -> ties keep lower idx, = top_k
        int p = KNN-1;
        while (p > 0 && dl[base+p-1] > d0){
          dl[base+p] = dl[base+p-1]; il[base+p] = il[base+p-1]; p--;
        }
        dl[base+p] = d0; il[base+p] = (unsigned short)(c0 + jj0);
        t19d = dl[base+KNN-1];
      }
      if (d1 < t19d){
        int p = KNN-1;
        while (p > 0 && dl[base+p-1] > d1){
          dl[base+p] = dl[base+p-1]; il[base+p] = il[base+p-1]; p--;
        }
        dl[base+p] = d1; il[base+p] = (unsigned short)(c0 + jj1);
        t19d = dl[base+KNN-1];
      }
    }
  }
  __syncthreads();
  // merge the 4 slot-lists of each query with lexicographic (d, idx) comparator
  if (slot == 0){
    int mb = tid*21;
    for (int s = 1; s < 4; s++){
      int sb = (s*64 + q_l)*21;
      for (int p = 0; p < KNN; p++){
        float d = dl[sb+p];
        unsigned short ci = il[sb+p];
        float fd = dl[mb+KNN-1];
        unsigned short fi = il[mb+KNN-1];
        if (d > fd || (d == fd && ci > fi)) break;   // sorted source: rest are worse
        int q = KNN-1;
        while (q > 0 && (dl[mb+q-1] > d ||
               (dl[mb+q-1] == d && il[mb+q-1] > ci))){
          dl[mb+q] = dl[mb+q-1]; il[mb+q] = il[mb+q-1]; q--;
        }
        dl[mb+q] = d; il[mb+q] = ci;
      }
    }
    for (int p = 0; p < KNN; p++) idx2[gi*KNN+p] = (int)il[mb+p];
  }
}

// ---------------- fast path: B2H = x1 @ Wbot[:, q-half] ----------------
__global__ __launch_bounds__(256) void k_B2h(const float* x1, const float* inb,
                                             int q, float* B2H){
  __shared__ __align__(16) float Wbh[4096];
  __shared__ __align__(16) float xsh[1024];
  int tid = threadIdx.x;
  const float* Wb = inb + IN_WBUF + WB_WBOT;
  for (int t = tid; t < 4096; t += 256){
    int r = t >> 6, cl = t & 63;
    Wbh[t] = Wb[r*128 + q*64 + cl];
  }
  int node0 = blockIdx.x * 16;
  for (int t = tid; t < 1024; t += 256) xsh[t] = x1[node0*64 + t];
  __syncthreads();
  int n_l = tid >> 4, cg = tid & 15;
  const float* xr = xsh + n_l*64;
  float4 acc = make_float4(0.f,0.f,0.f,0.f);
  #pragma unroll 8
  for (int d = 0; d < 64; d++){
    float v = xr[d];
    float4 w = *(const float4*)(Wbh + d*64 + cg*4);
    acc.x += v*w.x; acc.y += v*w.y; acc.z += v*w.z; acc.w += v*w.w;
  }
  *(float4*)(B2H + (node0 + n_l)*64 + cg*4) = acc;
}

// ---------------- fast path: x2 half = (x1_i@Wd + bc2) + max_j B2H[j] ----------------
__global__ __launch_bounds__(256) void k_x2h(const float* x1, const float* B2H,
                                             const float* inb, const int* idx2,
                                             int q, float* x2){
  __shared__ __align__(16) float Wdh[4096];
  __shared__ __align__(16) float xsh[256];
  int tid = threadIdx.x;
  const float* Wd = inb + IN_WBUF + WB_WD;
  for (int t = tid; t < 4096; t += 256){
    int r = t >> 6, cl = t & 63;
    Wdh[t] = Wd[r*128 + q*64 + cl];
  }
  int node0 = blockIdx.x * 4;
  xsh[tid] = x1[node0*64 + tid];
  __syncthreads();
  int n_l = tid >> 6, cl = tid & 63;
  int i = node0 + n_l;
  int b = i >> 10;
  const float* xr = xsh + n_l*64;
  float acc = inb[IN_BC2 + q*64 + cl];
  #pragma unroll 8
  for (int d = 0; d < 64; d++) acc += xr[d]*Wdh[d*64 + cl];
  float m = -FLT_MAX;
  for (int kk = 0; kk < KNN; kk++){
    int j = idx2[i*KNN + kk];
    m = fmaxf(m, B2H[((b<<10)+j)*64 + cl]);
  }
  x2[i*128 + q*64 + cl] = acc + m;
}

// ---------------- slow fallback: x2 direct, LDS-staged, no B2H buffer ----------------
__global__ __launch_bounds__(256) void k_x2d(const float* x1, const float* inb,
                                             const int* idx2, float* x2){
  __shared__ __align__(16) float Wdh[4096], Wbh[4096];
  __shared__ __align__(16) float xis[1024], xjs[1024];
  int tid = threadIdx.x;
  int q = blockIdx.x & 1;
  int node0 = (blockIdx.x >> 1) * 16;
  const float* Wd = inb + IN_WBUF + WB_WD;
  const float* Wb = inb + IN_WBUF + WB_WBOT;
  for (int t = tid; t < 4096; t += 256){
    int r = t >> 6, cl = t & 63;
    Wdh[t] = Wd[r*128 + q*64 + cl];
    Wbh[t] = Wb[r*128 + q*64 + cl];
  }
  for (int t = tid; t < 1024; t += 256) xis[t] = x1[node0*64 + t];
  __syncthreads();
  int n_l = tid >> 4, cg = tid & 15;
  int i = node0 + n_l, b = i >> 10;
  const float* xr = xis + n_l*64;
  float4 af = make_float4(inb[IN_BC2 + q*64 + cg*4],   inb[IN_BC2 + q*64 + cg*4+1],
                          inb[IN_BC2 + q*64 + cg*4+2], inb[IN_BC2 + q*64 + cg*4+3]);
  #pragma unroll 8
  for (int d = 0; d < 64; d++){
    float v = xr[d];
    float4 w = *(const float4*)(Wdh + d*64 + cg*4);
    af.x += v*w.x; af.y += v*w.y; af.z += v*w.z; af.w += v*w.w;
  }
  float4 mx = make_float4(-FLT_MAX,-FLT_MAX,-FLT_MAX,-FLT_MAX);
  for (int kk = 0; kk < KNN; kk++){
    __syncthreads();
    for (int t = tid; t < 1024; t += 256){
      int nn = t >> 6, r = t & 63;
      int jj = idx2[(node0+nn)*KNN + kk];
      xjs[t] = x1[((((node0+nn) >> 10) << 10) + jj)*64 + r];
    }
    __syncthreads();
    const float* xj = xjs + n_l*64;
    float4 acc = make_float4(0.f,0.f,0.f,0.f);
    #pragma unroll 8
    for (int d = 0; d < 64; d++){
      float v = xj[d];
      float4 w = *(const float4*)(Wbh + d*64 + cg*4);
      acc.x += v*w.x; acc.y += v*w.y; acc.z += v*w.z; acc.w += v*w.w;
    }
    mx.x = fmaxf(mx.x, acc.x); mx.y = fmaxf(mx.y, acc.y);
    mx.z = fmaxf(mx.z, acc.z); mx.w = fmaxf(mx.w, acc.w);
  }
  *(float4*)(x2 + i*128 + q*64 + cg*4) =
      make_float4(af.x+mx.x, af.y+mx.y, af.z+mx.z, af.w+mx.w);
}

// ---------------- lin (192->1024) + partial max over n-quarter ----------------
__global__ __launch_bounds__(256) void k_linpool(const float* x1, const float* x2,
    const float* inb, float* pool4){
  __shared__ __align__(16) float fst[192*36];
  __shared__ float red2[1024];
  int tid = threadIdx.x;
  int b = blockIdx.x >> 4, cq = (blockIdx.x >> 2) & 3, nh = blockIdx.x & 3;
  int cg = tid & 63, n8 = tid >> 6;
  int cbase = cq*256 + cg*4;
  const float* Wl = inb + IN_WBUF + WB_WL;
  float m0 = -FLT_MAX, m1 = -FLT_MAX, m2 = -FLT_MAX, m3 = -FLT_MAX;
  for (int ng = 0; ng < 8; ng++){
    __syncthreads();
    for (int t = tid; t < 6144; t += 256){
      int n_l = t / 192, dd = t - n_l*192;
      int gi = b*1024 + nh*256 + ng*32 + n_l;
      fst[dd*36 + n_l] = (dd < 64) ? x1[gi*64 + dd] : x2[gi*128 + dd - 64];
    }
    __syncthreads();
    float acc[8][4];
    #pragma unroll
    for (int n = 0; n < 8; n++){ acc[n][0]=0; acc[n][1]=0; acc[n][2]=0; acc[n][3]=0; }
    #pragma unroll 4
    for (int d = 0; d < 192; d++){
      float4 w = *(const float4*)(Wl + d*1024 + cbase);
      const float* fr = fst + d*36 + n8*8;
      float4 f0 = *(const float4*)(fr);
      float4 f1 = *(const float4*)(fr + 4);
      float fv[8] = {f0.x, f0.y, f0.z, f0.w, f1.x, f1.y, f1.z, f1.w};
      #pragma unroll
      for (int n = 0; n < 8; n++){
        acc[n][0] += fv[n]*w.x; acc[n][1] += fv[n]*w.y;
        acc[n][2] += fv[n]*w.z; acc[n][3] += fv[n]*w.w;
      }
    }
    #pragma unroll
    for (int n = 0; n < 8; n++){
      m0 = fmaxf(m0, acc[n][0]); m1 = fmaxf(m1, acc[n][1]);
      m2 = fmaxf(m2, acc[n][2]); m3 = fmaxf(m3, acc[n][3]);
    }
  }
  red2[n8*256 + cg*4]   = m0;  red2[n8*256 + cg*4+1] = m1;
  red2[n8*256 + cg*4+2] = m2;  red2[n8*256 + cg*4+3] = m3;
  __syncthreads();
  if (n8 == 0){
    #pragma unroll
    for (int u = 0; u < 4; u++){
      int cc = cg*4 + u;
      float m = fmaxf(fmaxf(red2[cc], red2[256+cc]), fmaxf(red2[512+cc], red2[768+cc]));
      pool4[nh*32768 + b*1024 + cbase + u] = m;     // bias applied in k_head
    }
  }
}

// ---------------- head MLP: reduce pool4 + 1024->512->256->40 (fp32 out) ----------------
__global__ __launch_bounds__(256) void k_head(const float* pool4, const float* inb,
                                              float* out){
  __shared__ float pl[1024];
  __shared__ float s1[512];
  __shared__ float s2[256];
  int b = blockIdx.x, tid = threadIdx.x;
  const float* Wm1 = inb + IN_WBUF + WB_WM1;
  const float* Wm2 = inb + IN_WBUF + WB_WM2;
  const float* Wm3 = inb + IN_WBUF + WB_WM3;
  for (int t = tid; t < 1024; t += 256){
    float m = fmaxf(fmaxf(pool4[b*1024 + t],         pool4[32768 + b*1024 + t]),
                    fmaxf(pool4[65536 + b*1024 + t], pool4[98304 + b*1024 + t]));
    pl[t] = m + inb[IN_BL + t];
  }
  __syncthreads();
  for (int c = tid; c < 512; c += 256){
    float acc = inb[IN_BM1 + c];
    #pragma unroll 4
    for (int d = 0; d < 1024; d++) acc += pl[d]*Wm1[d*512 + c];
    s1[c] = fmaxf(acc, 0.f);
  }
  __syncthreads();
  {
    int c = tid;
    float acc = inb[IN_BM2 + c];
    #pragma unroll 4
    for (int d = 0; d < 512; d++) acc += s1[d]*Wm2[d*256 + c];
    s2[c] = fmaxf(acc, 0.f);
  }
  __syncthreads();
  if (tid < 40){
    float acc = inb[IN_BM3 + tid];
    #pragma unroll 4
    for (int d = 0; d < 256; d++) acc += s2[d]*Wm3[d*40 + tid];
    out[b*40 + tid] = acc;
  }
}

extern "C" void kernel_launch(void* const* d_in, const int* in_sizes, int n_in,
                              void* d_out, int out_size, void* d_ws, size_t ws_size,
                              hipStream_t stream){
  float* ws     = (float*)d_ws;
  double* stats = (double*)d_ws;
  int*   flag   = (int*)d_ws + OFF_FLAG;
  float* inb    = ws + OFF_INB;
  int*   idx    = (int*)d_ws + OFF_IDX;     // idx1 early, idx2 late
  float* x1p    = ws + OFF_X1;
  float* x2p    = ws + OFF_X2;
  float* a1     = ws + OFF_X2;              // a1/c1 alias x2 region (dead before x2 written)
  float* c1     = ws + OFF_C1;
  float* pool4  = ws + OFF_POOL;
  float* B2H    = ws + OFF_B2H;
  bool fast = ws_size >= (size_t)FAST_END * 4u;

  hipMemsetAsync(stats, 0, 256*sizeof(double), stream);
  k_sniff<<<1, 64, 0, stream>>>(d_in[0], flag);
  k_cvt<<<3859, 256, 0, stream>>>(
      d_in[0], d_in[1], d_in[2], d_in[3], d_in[4], d_in[5], d_in[6], d_in[7],
      d_in[8], d_in[9], d_in[10], d_in[11], d_in[12], d_in[13], d_in[14],
      d_in[15], d_in[16], d_in[17], d_in[18], d_in[19], d_in[20], flag, inb);
  k_prep1<<<8192, 256, 0, stream>>>(inb, a1, c1);
  k_knn1<<<512, 256, 0, stream>>>(inb, idx);
  k_stats1<<<640, 256, 0, stream>>>(a1, c1, idx, stats);
  k_stats2<<<2560, 256, 0, stream>>>(a1, c1, idx, inb, stats);
  k_x1<<<8192, 256, 0, stream>>>(a1, c1, idx, inb, stats, x1p);
  k_knn2<<<512, 256, 0, stream>>>(x1p, idx);
  if (fast){
    k_B2h<<<2048, 256, 0, stream>>>(x1p, inb, 0, B2H);
    k_x2h<<<8192, 256, 0, stream>>>(x1p, B2H, inb, idx, 0, x2p);
    k_B2h<<<2048, 256, 0, stream>>>(x1p, inb, 1, B2H);
    k_x2h<<<8192, 256, 0, stream>>>(x1p, B2H, inb, idx, 1, x2p);
  } else {
    k_x2d<<<4096, 256, 0, stream>>>(x1p, inb, idx, x2p);
  }
  k_linpool<<<512, 256, 0, stream>>>(x1p, x2p, inb, pool4);
  k_head<<<32, 256, 0, stream>>>(pool4, inb, (float*)d_out);
}